// Round 4
// baseline (361.571 us; speedup 1.0000x reference)
//
#include <hip/hip_runtime.h>

// FastIMDCT4: B=32, T=1024, n_fft=2048, hop=1024.
// out[b, q*1024+r] = frames[b,q,1024+r] + frames[b,q+1,r], q in [0,1023)
// frames[m] = sign[m]*window[m]/512 * inter[post[m]];  inter from 512-pt FFT.
//
// R3: 8-wave blocks, 7 chunks/block, reg 512-pt FFT -> LDS -> extract. 82.9us.
// R4: LDS twiddles: VALU 75->48%, dur unchanged.
// R5: 8x8x8 FFT, DS halved, conflicts 4.9M->1.2M, dur unchanged.
//     => all pipes ~40-45%: convoy/latency-bound.
// R6: persistent+prefetch REGRESSED (94.9us): VGPR 68 > 64 -> waves/CU halved
//     -> only 2 of 4 blocks/CU resident, half the grid serialized (occ 20%).
// R7: fix R6's two failures:
//     - __launch_bounds__(512, 8): force VGPR<=64 so 4 blocks/CU fit.
//     - prefetch issued right after pre-twiddle frees v (sched_barrier-pinned),
//       hiding load latency under the FFT main body + extraction, not just
//       extraction. Division-free group bookkeeping (1024 = 6*147 + 142).

#define CHUNKS 1023
#define CPB 7              // chunks per group
#define BPB 147            // groups per batch: ceil(1023/7)
#define NGROUPS (32 * BPB) // 4704
#define GRID 1024          // persistent blocks: 256 CU x 4

__device__ __forceinline__ float2 cmul(float2 a, float2 b) {
    return make_float2(a.x * b.x - a.y * b.y, a.x * b.y + a.y * b.x);
}
__device__ __forceinline__ float2 cadd(float2 a, float2 b) {
    return make_float2(a.x + b.x, a.y + b.y);
}
__device__ __forceinline__ float2 csub(float2 a, float2 b) {
    return make_float2(a.x - b.x, a.y - b.y);
}
// (cos,sin) of 2*pi*rev — v_cos_f32/v_sin_f32 take revolutions; |rev| < 1 here.
__device__ __forceinline__ float2 twid(float rev) {
    return make_float2(__builtin_amdgcn_cosf(rev), __builtin_amdgcn_sinf(rev));
}

// post[] / sign[] closed forms (verified R1/R2: absmax 9.8e-4):
__device__ __forceinline__ void postmap(int m, int& p, float& sgn) {
    bool even = ((m & 1) == 0);
    if (m < 512)       p = even ? (m + 512)  : (512 - m);
    else if (m < 1536) p = even ? (m - 511)  : (1535 - m);
    else               p = even ? (m - 1536) : (2560 - m);
    float s1 = even ? 1.0f : -1.0f;
    sgn = (m < 1536) ? s1 : -s1;
}

__device__ __forceinline__ int brev3(int r) {
    return ((r & 1) << 2) | (r & 2) | ((r >> 2) & 1);
}

// 8-pt DFT, natural input order, output digit d lives in reg brev3(d).
__device__ __forceinline__ void radix8(float2 c[8]) {
    const float RH = 0.70710678118654752f;
    {   // stage 1 (half=4)
        float2 u0 = c[0], u1 = c[1], u2 = c[2], u3 = c[3];
        float2 l0 = c[4], l1 = c[5], l2 = c[6], l3 = c[7];
        float2 t1 = csub(u1, l1), t2 = csub(u2, l2), t3 = csub(u3, l3);
        c[0] = cadd(u0, l0); c[4] = csub(u0, l0);
        c[1] = cadd(u1, l1); c[5] = cmul(make_float2(RH, -RH), t1);
        c[2] = cadd(u2, l2); c[6] = make_float2(t2.y, -t2.x);           // * -i
        c[3] = cadd(u3, l3); c[7] = cmul(make_float2(-RH, -RH), t3);
    }
    #pragma unroll
    for (int b = 0; b < 8; b += 4) {  // stage 2 (half=2)
        float2 u0 = c[b], u1 = c[b + 1], d0 = c[b + 2], d1 = c[b + 3];
        float2 t = csub(u1, d1);
        c[b] = cadd(u0, d0);
        c[b + 2] = csub(u0, d0);
        c[b + 1] = cadd(u1, d1);
        c[b + 3] = make_float2(t.y, -t.x);                              // * -i
    }
    #pragma unroll
    for (int b = 0; b < 8; b += 2) {  // stage 3 (half=1)
        float2 u = c[b], d = c[b + 1];
        c[b] = cadd(u, d); c[b + 1] = csub(u, d);
    }
}

// Apply w^digit to each reg (digit(r) = brev3(r)): power chain in digit order.
__device__ __forceinline__ void midchain(float2 c[8], float2 w) {
    float2 wc = w;
    c[4] = cmul(wc, c[4]);                    // digit 1
    wc = cmul(wc, w); c[2] = cmul(wc, c[2]);  // digit 2
    wc = cmul(wc, w); c[6] = cmul(wc, c[6]);  // digit 3
    wc = cmul(wc, w); c[1] = cmul(wc, c[1]);  // digit 4
    wc = cmul(wc, w); c[5] = cmul(wc, c[5]);  // digit 5
    wc = cmul(wc, w); c[3] = cmul(wc, c[3]);  // digit 6
    wc = cmul(wc, w); c[7] = cmul(wc, c[7]);  // digit 7
}

// W32^r = W2048^{64r} = exp(-2*pi*i*r/32), exact compile-time constants.
#define K32_DECL \
    const float K32C[8] = {1.0f, 0.98078528040323044913f, 0.92387953251128675613f, \
                           0.83146961230254523708f, 0.70710678118654752440f,       \
                           0.55557023301960222474f, 0.38268343236508977173f,       \
                           0.19509032201612826785f};                               \
    const float K32S[8] = {0.0f, -0.19509032201612826785f, -0.38268343236508977173f,\
                           -0.55557023301960222474f, -0.70710678118654752440f,     \
                           -0.83146961230254523708f, -0.92387953251128675613f,     \
                           -0.98078528040323044913f};

__device__ __forceinline__ void load_frame(const float* __restrict__ row, int lane,
                                           float2 v[8]) {
    const float2* row2 = (const float2*)row;
    #pragma unroll
    for (int r = 0; r < 8; ++r) v[r] = row2[64 * r + lane];   // 512B/instr coalesced
}

// Pre-twiddle: consumes v (dead afterwards), produces c.
// c_n = W2048^{n+1/8} * (row[2n] + i*row[1023-2n]); imag lives in lane^63's
// v[7-r].y. W2048^{64r+lane+1/8} = T1b[lane] * K32[r].
__device__ __forceinline__ void fft_pre(const float2 v[8], int lane, float2 c[8],
                                        const float2* __restrict__ T1b) {
    K32_DECL
    float2 base = T1b[lane];
    #pragma unroll
    for (int r = 0; r < 8; ++r) {
        float im = __shfl_xor(v[7 - r].y, 63);
        float2 tw = (r == 0) ? base : cmul(base, make_float2(K32C[r], K32S[r]));
        c[r] = cmul(tw, make_float2(v[r].x, im));
    }
}

// Remainder of the 512-pt FFT (8x8x8, verified R5): three radix-8 stages with
// two barrier-free per-wave LDS redistributes (XOR-swizzled, conflict-free) in
// the wave's own slot; natural-k split-plane store.
__device__ __forceinline__ void fft_rest(float2 c[8], int lane,
                                         float* __restrict__ planes,
                                         const float2* __restrict__ TM,
                                         const float2* __restrict__ TM2,
                                         const float2* __restrict__ TP2) {
    K32_DECL
    float2* scratch = (float2*)planes;
    const int lh = lane >> 3;
    const int ll = lane & 7;

    // stage 1: radix-8 over n1 -> digit k1 (reg brev3(k1))
    radix8(c);
    midchain(c, TM[lane]);                       // * W512^{n2*k1}, n2 = lane

    // redistribute 1: (k1 regs, lane=(m1,m0)) -> (m1 regs, lane=(k1,m0))
    // idx(k1,m1,m0) = k1*64 + (m1^k1)*8 + m0  (conflict-free both sides)
    #pragma unroll
    for (int r = 0; r < 8; ++r) {
        const int q = brev3(r);
        scratch[q * 64 + (lh ^ q) * 8 + ll] = c[r];
    }
    asm volatile("" ::: "memory");
    #pragma unroll
    for (int r = 0; r < 8; ++r)
        c[r] = scratch[lh * 64 + (r ^ lh) * 8 + ll];   // now lh=k1, ll=m0

    // stage 2: radix-8 over m1 -> digit j1
    radix8(c);
    midchain(c, TM2[ll]);                        // * W64^{m0*j1}

    // redistribute 2: (j1 regs, lane=(k1,m0)) -> (m0 regs, lane=(k1,j1))
    // idx(k1,j1,m0) = k1*64 + (j1^k1)*8 + (m0^j1)
    #pragma unroll
    for (int r = 0; r < 8; ++r) {
        const int j1 = brev3(r);
        scratch[lh * 64 + (j1 ^ lh) * 8 + (ll ^ j1)] = c[r];
    }
    asm volatile("" ::: "memory");
    #pragma unroll
    for (int r = 0; r < 8; ++r)
        c[r] = scratch[lh * 64 + (ll ^ lh) * 8 + (r ^ ll)];  // now ll = j1

    // stage 3: radix-8 over m0 -> digit j2
    radix8(c);

    // post twiddle + natural-order store: k = 64*j2 + 8*j1 + k1
    float2 base2 = TP2[lane];
    const int kbase = 8 * ll + lh;
    #pragma unroll
    for (int j = 0; j < 8; ++j) {
        float2 tw = (j == 0) ? base2 : cmul(base2, make_float2(K32C[j], K32S[j]));
        float2 dv = cmul(tw, c[brev3(j)]);
        planes[64 * j + kbase]       = dv.x;
        planes[512 + 64 * j + kbase] = dv.y;
    }
}

// 8 waves/EU minimum -> VGPR capped at 64 -> 4 blocks/CU (R6 broke this: 68).
__global__ __launch_bounds__(512, 8) void imdct_kernel(
        const float* __restrict__ signal,
        const float* __restrict__ window,
        float* __restrict__ out) {
    __shared__ float lds[8][1024];   // 8 frames x (Re[512] | Im[512]) = 32 KB
    __shared__ float2 T1b[64];       // W2048^{l+1/8}
    __shared__ float2 TM[64];        // W512^{l}
    __shared__ float2 TP2[64];       // W2048^{8*(l&7)+(l>>3)+1/8}
    __shared__ float2 TM2[8];        // W64^{l}

    const int tid = threadIdx.x;
    const int lane = tid & 63;
    const int w = tid >> 6;

    // ---- table init: once per persistent block ----
    if (tid < 64) {
        T1b[tid] = twid(-((float)tid + 0.125f) * (1.0f / 2048.0f));
        TM[tid]  = twid(-(float)tid * (1.0f / 512.0f));
        TP2[tid] = twid(-((float)(8 * (tid & 7) + (tid >> 3)) + 0.125f) * (1.0f / 2048.0f));
    }
    if (tid < 8) TM2[tid] = twid(-(float)tid * (1.0f / 64.0f));

    // ---- extraction constants: tid-only, hoisted out of the persistent loop
    const int r = 2 * tid;
    int p00, p01, p10, p11; float s00, s01, s10, s11;
    postmap(1024 + r,     p00, s00);
    postmap(1024 + r + 1, p01, s01);
    postmap(r,            p10, s10);
    postmap(r + 1,        p11, s11);
    const float2 wh = *(const float2*)(window + 1024 + r);
    const float2 wl = *(const float2*)(window + r);
    const float a00 = s00 * wh.x * (1.0f / 512.0f);
    const float a01 = s01 * wh.y * (1.0f / 512.0f);
    const float a10 = s10 * wl.x * (1.0f / 512.0f);
    const float a11 = s11 * wl.y * (1.0f / 512.0f);
    const int o00 = (p00 & 1) * 512 + (p00 >> 1);
    const int o01 = (p01 & 1) * 512 + (p01 >> 1);
    const int o10 = (p10 & 1) * 512 + (p10 >> 1);
    const int o11 = (p11 & 1) * 512 + (p11 >> 1);

    // ---- prologue: first group's loads ----
    int g = blockIdx.x;            // < 1024 < NGROUPS
    int b = g / BPB;
    int cb = g - b * BPB;          // group index within batch
    int q0 = cb * CPB;
    bool act = (q0 + w <= 1023);
    float2 v[8];
    if (act) load_frame(signal + (size_t)(b * 1024 + q0 + w) * 1024, lane, v);
    __syncthreads();   // tables visible (full drain OK once, in prologue)

    for (;;) {
        // Pre-twiddle consumes v -> c; v is then free for the prefetch.
        float2 c[8];
        if (act) fft_pre(v, lane, c, T1b);

        // Next-group bookkeeping, division-free: +1024 groups = +6 batches
        // + 142 within-batch (1024 = 6*147 + 142).
        const int gn = g + GRID;
        const bool have_next = (gn < NGROUPS);
        int bn = b, cbn = cb;
        if (have_next) {
            bn = b + 6; cbn = cb + (GRID - 6 * BPB);
            if (cbn >= BPB) { cbn -= BPB; bn += 1; }
        }
        const int qn0 = cbn * CPB;
        const bool actn = have_next && (qn0 + w <= 1023);
        // Prefetch NOW: latency hides under fft_rest (~800+ cyc) + extraction.
        if (actn) load_frame(signal + (size_t)(bn * 1024 + qn0 + w) * 1024, lane, v);
        __builtin_amdgcn_sched_barrier(0);   // pin prefetch issue before FFT body

        if (act) fft_rest(c, lane, &lds[w][0], TM, TM2, TP2);

        // Raw barrier with lgkmcnt(0) only: planes visible to all waves, but
        // prefetch loads (vmcnt) stay in flight across the barrier.
        asm volatile("s_waitcnt lgkmcnt(0)" ::: "memory");
        __builtin_amdgcn_sched_barrier(0);
        __builtin_amdgcn_s_barrier();
        asm volatile("" ::: "memory");

        // Extraction for group g (DS reads + global stores; stores drain under
        // the next iteration's FFT).
        float* orow_base = out + (size_t)b * (CHUNKS * 1024);
        #pragma unroll
        for (int j = 0; j < CPB; ++j) {
            const int qj = q0 + j;
            if (qj > 1022) break;            // block-uniform
            const float* f0 = &lds[j][0];
            const float* f1 = &lds[j + 1][0];
            float2 o;
            o.x = a00 * f0[o00] + a10 * f1[o10];
            o.y = a01 * f0[o01] + a11 * f1[o11];
            *(float2*)(orow_base + (size_t)qj * 1024 + r) = o;
        }

        if (!have_next) break;

        // All waves' extraction reads are consumed (stores issued) before
        // arrival here; barrier alone protects lds from next FFT's writes
        // (first DS write of next iter is deep inside fft_rest).
        asm volatile("" ::: "memory");
        __builtin_amdgcn_s_barrier();
        asm volatile("" ::: "memory");

        g = gn; b = bn; cb = cbn; q0 = qn0; act = actn;
    }
}

extern "C" void kernel_launch(void* const* d_in, const int* in_sizes, int n_in,
                              void* d_out, int out_size, void* d_ws, size_t ws_size,
                              hipStream_t stream) {
    const float* signal = (const float*)d_in[0];
    const float* window = (const float*)d_in[1];
    float* out = (float*)d_out;
    // 1024 persistent blocks (4/CU), grid-striding 4704 chunk-groups.
    imdct_kernel<<<dim3(GRID), dim3(512), 0, stream>>>(signal, window, out);
}

// Round 5
// 346.723 us; speedup vs baseline: 1.0428x; 1.0428x over previous
//
#include <hip/hip_runtime.h>

// FastIMDCT4: B=32, T=1024, n_fft=2048, hop=1024.
// out[b, q*1024+r] = frames[b,q,1024+r] + frames[b,q+1,r], q in [0,1023)
// frames[m] = sign[m]*window[m]/512 * inter[post[m]];  inter from 512-pt FFT.
//
// R3: 8-wave blocks, 7 chunks/block, reg 512-pt FFT -> LDS -> extract. 82.9us.
// R4: LDS twiddles: VALU 75->48%, dur unchanged.
// R5: 8x8x8 FFT, DS halved, conflicts 4.9M->1.2M, dur unchanged.
//     => all pipes ~40-45%: convoy/latency-bound.
// R6: persistent+prefetch: VGPR 68 -> 2/4 blocks resident -> 94.9us.
// R7: __launch_bounds__(512,8) was interpreted as 8 BLOCKS/CU -> VGPR capped
//     at 32 -> heavy scratch spill (FETCH 75->394MB, WRITE 131->406MB), 212us.
//     BUT: persistent grid held 84% occupancy, and HBM sustained 3.9 TB/s.
// R8: same pipeline, register problem fixed properly:
//     - amdgpu_waves_per_eu(8): direct backend attr -> VGPR cap 64, 8 w/SIMD.
//     - true live-set cut below 64: extraction offsets packed 4->2 regs
//       (unpacked only after c[] dies), q0/orow_base recomputed at use.

#define CHUNKS 1023
#define CPB 7              // chunks per group
#define BPB 147            // groups per batch: ceil(1023/7)
#define NGROUPS (32 * BPB) // 4704
#define GRID 1024          // persistent blocks: 256 CU x 4

__device__ __forceinline__ float2 cmul(float2 a, float2 b) {
    return make_float2(a.x * b.x - a.y * b.y, a.x * b.y + a.y * b.x);
}
__device__ __forceinline__ float2 cadd(float2 a, float2 b) {
    return make_float2(a.x + b.x, a.y + b.y);
}
__device__ __forceinline__ float2 csub(float2 a, float2 b) {
    return make_float2(a.x - b.x, a.y - b.y);
}
// (cos,sin) of 2*pi*rev — v_cos_f32/v_sin_f32 take revolutions; |rev| < 1 here.
__device__ __forceinline__ float2 twid(float rev) {
    return make_float2(__builtin_amdgcn_cosf(rev), __builtin_amdgcn_sinf(rev));
}

// post[] / sign[] closed forms (verified R1/R2: absmax 9.8e-4):
__device__ __forceinline__ void postmap(int m, int& p, float& sgn) {
    bool even = ((m & 1) == 0);
    if (m < 512)       p = even ? (m + 512)  : (512 - m);
    else if (m < 1536) p = even ? (m - 511)  : (1535 - m);
    else               p = even ? (m - 1536) : (2560 - m);
    float s1 = even ? 1.0f : -1.0f;
    sgn = (m < 1536) ? s1 : -s1;
}

__device__ __forceinline__ int brev3(int r) {
    return ((r & 1) << 2) | (r & 2) | ((r >> 2) & 1);
}

// 8-pt DFT, natural input order, output digit d lives in reg brev3(d).
__device__ __forceinline__ void radix8(float2 c[8]) {
    const float RH = 0.70710678118654752f;
    {   // stage 1 (half=4)
        float2 u0 = c[0], u1 = c[1], u2 = c[2], u3 = c[3];
        float2 l0 = c[4], l1 = c[5], l2 = c[6], l3 = c[7];
        float2 t1 = csub(u1, l1), t2 = csub(u2, l2), t3 = csub(u3, l3);
        c[0] = cadd(u0, l0); c[4] = csub(u0, l0);
        c[1] = cadd(u1, l1); c[5] = cmul(make_float2(RH, -RH), t1);
        c[2] = cadd(u2, l2); c[6] = make_float2(t2.y, -t2.x);           // * -i
        c[3] = cadd(u3, l3); c[7] = cmul(make_float2(-RH, -RH), t3);
    }
    #pragma unroll
    for (int b = 0; b < 8; b += 4) {  // stage 2 (half=2)
        float2 u0 = c[b], u1 = c[b + 1], d0 = c[b + 2], d1 = c[b + 3];
        float2 t = csub(u1, d1);
        c[b] = cadd(u0, d0);
        c[b + 2] = csub(u0, d0);
        c[b + 1] = cadd(u1, d1);
        c[b + 3] = make_float2(t.y, -t.x);                              // * -i
    }
    #pragma unroll
    for (int b = 0; b < 8; b += 2) {  // stage 3 (half=1)
        float2 u = c[b], d = c[b + 1];
        c[b] = cadd(u, d); c[b + 1] = csub(u, d);
    }
}

// Apply w^digit to each reg (digit(r) = brev3(r)): power chain in digit order.
__device__ __forceinline__ void midchain(float2 c[8], float2 w) {
    float2 wc = w;
    c[4] = cmul(wc, c[4]);                    // digit 1
    wc = cmul(wc, w); c[2] = cmul(wc, c[2]);  // digit 2
    wc = cmul(wc, w); c[6] = cmul(wc, c[6]);  // digit 3
    wc = cmul(wc, w); c[1] = cmul(wc, c[1]);  // digit 4
    wc = cmul(wc, w); c[5] = cmul(wc, c[5]);  // digit 5
    wc = cmul(wc, w); c[3] = cmul(wc, c[3]);  // digit 6
    wc = cmul(wc, w); c[7] = cmul(wc, c[7]);  // digit 7
}

// W32^r = W2048^{64r} = exp(-2*pi*i*r/32), exact compile-time constants.
#define K32_DECL \
    const float K32C[8] = {1.0f, 0.98078528040323044913f, 0.92387953251128675613f, \
                           0.83146961230254523708f, 0.70710678118654752440f,       \
                           0.55557023301960222474f, 0.38268343236508977173f,       \
                           0.19509032201612826785f};                               \
    const float K32S[8] = {0.0f, -0.19509032201612826785f, -0.38268343236508977173f,\
                           -0.55557023301960222474f, -0.70710678118654752440f,     \
                           -0.83146961230254523708f, -0.92387953251128675613f,     \
                           -0.98078528040323044913f};

__device__ __forceinline__ void load_frame(const float* __restrict__ row, int lane,
                                           float2 v[8]) {
    const float2* row2 = (const float2*)row;
    #pragma unroll
    for (int r = 0; r < 8; ++r) v[r] = row2[64 * r + lane];   // 512B/instr coalesced
}

// Pre-twiddle: consumes v (dead afterwards), produces c.
// c_n = W2048^{n+1/8} * (row[2n] + i*row[1023-2n]); imag lives in lane^63's
// v[7-r].y. W2048^{64r+lane+1/8} = T1b[lane] * K32[r].
__device__ __forceinline__ void fft_pre(const float2 v[8], int lane, float2 c[8],
                                        const float2* __restrict__ T1b) {
    K32_DECL
    float2 base = T1b[lane];
    #pragma unroll
    for (int r = 0; r < 8; ++r) {
        float im = __shfl_xor(v[7 - r].y, 63);
        float2 tw = (r == 0) ? base : cmul(base, make_float2(K32C[r], K32S[r]));
        c[r] = cmul(tw, make_float2(v[r].x, im));
    }
}

// Remainder of the 512-pt FFT (8x8x8, verified R5): three radix-8 stages with
// two barrier-free per-wave LDS redistributes (XOR-swizzled, conflict-free) in
// the wave's own slot; natural-k split-plane store.
__device__ __forceinline__ void fft_rest(float2 c[8], int lane,
                                         float* __restrict__ planes,
                                         const float2* __restrict__ TM,
                                         const float2* __restrict__ TM2,
                                         const float2* __restrict__ TP2) {
    K32_DECL
    float2* scratch = (float2*)planes;
    const int lh = lane >> 3;
    const int ll = lane & 7;

    // stage 1: radix-8 over n1 -> digit k1 (reg brev3(k1))
    radix8(c);
    midchain(c, TM[lane]);                       // * W512^{n2*k1}, n2 = lane

    // redistribute 1: (k1 regs, lane=(m1,m0)) -> (m1 regs, lane=(k1,m0))
    // idx(k1,m1,m0) = k1*64 + (m1^k1)*8 + m0  (conflict-free both sides)
    #pragma unroll
    for (int r = 0; r < 8; ++r) {
        const int q = brev3(r);
        scratch[q * 64 + (lh ^ q) * 8 + ll] = c[r];
    }
    asm volatile("" ::: "memory");
    #pragma unroll
    for (int r = 0; r < 8; ++r)
        c[r] = scratch[lh * 64 + (r ^ lh) * 8 + ll];   // now lh=k1, ll=m0

    // stage 2: radix-8 over m1 -> digit j1
    radix8(c);
    midchain(c, TM2[ll]);                        // * W64^{m0*j1}

    // redistribute 2: (j1 regs, lane=(k1,m0)) -> (m0 regs, lane=(k1,j1))
    // idx(k1,j1,m0) = k1*64 + (j1^k1)*8 + (m0^j1)
    #pragma unroll
    for (int r = 0; r < 8; ++r) {
        const int j1 = brev3(r);
        scratch[lh * 64 + (j1 ^ lh) * 8 + (ll ^ j1)] = c[r];
    }
    asm volatile("" ::: "memory");
    #pragma unroll
    for (int r = 0; r < 8; ++r)
        c[r] = scratch[lh * 64 + (ll ^ lh) * 8 + (r ^ ll)];  // now ll = j1

    // stage 3: radix-8 over m0 -> digit j2
    radix8(c);

    // post twiddle + natural-order store: k = 64*j2 + 8*j1 + k1
    float2 base2 = TP2[lane];
    const int kbase = 8 * ll + lh;
    #pragma unroll
    for (int j = 0; j < 8; ++j) {
        float2 tw = (j == 0) ? base2 : cmul(base2, make_float2(K32C[j], K32S[j]));
        float2 dv = cmul(tw, c[brev3(j)]);
        planes[64 * j + kbase]       = dv.x;
        planes[512 + 64 * j + kbase] = dv.y;
    }
}

// waves_per_eu(8): unambiguous backend attr -> VGPR cap 512/8 = 64, 8 w/SIMD,
// 4 blocks/CU. (R7's __launch_bounds__(512,8) acted as 8 BLOCKS/CU -> cap 32.)
__global__ __launch_bounds__(512)
__attribute__((amdgpu_waves_per_eu(8)))
void imdct_kernel(
        const float* __restrict__ signal,
        const float* __restrict__ window,
        float* __restrict__ out) {
    __shared__ float lds[8][1024];   // 8 frames x (Re[512] | Im[512]) = 32 KB
    __shared__ float2 T1b[64];       // W2048^{l+1/8}
    __shared__ float2 TM[64];        // W512^{l}
    __shared__ float2 TP2[64];       // W2048^{8*(l&7)+(l>>3)+1/8}
    __shared__ float2 TM2[8];        // W64^{l}

    const int tid = threadIdx.x;
    const int lane = tid & 63;
    const int w = tid >> 6;

    // ---- table init: once per persistent block ----
    if (tid < 64) {
        T1b[tid] = twid(-((float)tid + 0.125f) * (1.0f / 2048.0f));
        TM[tid]  = twid(-(float)tid * (1.0f / 512.0f));
        TP2[tid] = twid(-((float)(8 * (tid & 7) + (tid >> 3)) + 0.125f) * (1.0f / 2048.0f));
    }
    if (tid < 8) TM2[tid] = twid(-(float)tid * (1.0f / 64.0f));

    // ---- extraction constants (tid-only, persistent-loop invariant).
    // Offsets packed 2-per-reg so only 2 VGPRs stay live through the FFT;
    // unpacked after c[] dies. Coefficients: 4 VGPRs.
    float a00, a01, a10, a11;
    unsigned po_hi, po_lo;           // (o01<<16)|o00, (o11<<16)|o10
    {
        const int r = 2 * tid;
        int p00, p01, p10, p11; float s00, s01, s10, s11;
        postmap(1024 + r,     p00, s00);
        postmap(1024 + r + 1, p01, s01);
        postmap(r,            p10, s10);
        postmap(r + 1,        p11, s11);
        const float2 wh = *(const float2*)(window + 1024 + r);
        const float2 wl = *(const float2*)(window + r);
        a00 = s00 * wh.x * (1.0f / 512.0f);
        a01 = s01 * wh.y * (1.0f / 512.0f);
        a10 = s10 * wl.x * (1.0f / 512.0f);
        a11 = s11 * wl.y * (1.0f / 512.0f);
        const unsigned o00 = (p00 & 1) * 512 + (p00 >> 1);
        const unsigned o01 = (p01 & 1) * 512 + (p01 >> 1);
        const unsigned o10 = (p10 & 1) * 512 + (p10 >> 1);
        const unsigned o11 = (p11 & 1) * 512 + (p11 >> 1);
        po_hi = (o01 << 16) | o00;
        po_lo = (o11 << 16) | o10;
    }

    // ---- prologue: first group's loads ----
    int g = blockIdx.x;            // < 1024 < NGROUPS
    int b = g / BPB;
    int cb = g - b * BPB;          // group index within batch
    bool act = (cb * CPB + w <= 1023);
    float2 v[8];
    if (act) load_frame(signal + (size_t)(b * 1024 + cb * CPB + w) * 1024, lane, v);
    __syncthreads();   // tables visible (full drain OK once, in prologue)

    for (;;) {
        // Pre-twiddle consumes v -> c; v is then free for the prefetch.
        float2 c[8];
        if (act) fft_pre(v, lane, c, T1b);

        // Next-group bookkeeping, division-free: +1024 groups = +6 batches
        // + 142 within-batch (1024 = 6*147 + 142).
        const int gn = g + GRID;
        const bool have_next = (gn < NGROUPS);
        int bn = b, cbn = cb;
        if (have_next) {
            bn = b + 6; cbn = cb + (GRID - 6 * BPB);
            if (cbn >= BPB) { cbn -= BPB; bn += 1; }
        }
        const bool actn = have_next && (cbn * CPB + w <= 1023);
        // Prefetch NOW: latency hides under fft_rest (~800+ cyc) + extraction.
        if (actn) load_frame(signal + (size_t)(bn * 1024 + cbn * CPB + w) * 1024, lane, v);
        __builtin_amdgcn_sched_barrier(0);   // pin prefetch issue before FFT body

        if (act) fft_rest(c, lane, &lds[w][0], TM, TM2, TP2);

        // Raw barrier with lgkmcnt(0) only: planes visible to all waves, but
        // prefetch loads (vmcnt) stay in flight across the barrier.
        asm volatile("s_waitcnt lgkmcnt(0)" ::: "memory");
        __builtin_amdgcn_sched_barrier(0);
        __builtin_amdgcn_s_barrier();
        asm volatile("" ::: "memory");

        // Extraction for group g. c[] is dead here: unpack offsets into the
        // freed registers. Stores drain under the next iteration's FFT.
        {
            const int o00 = po_hi & 0xFFFF, o01 = po_hi >> 16;
            const int o10 = po_lo & 0xFFFF, o11 = po_lo >> 16;
            const int r = 2 * tid;
            const int q0 = cb * CPB;
            float* orow_base = out + (size_t)b * (CHUNKS * 1024);
            #pragma unroll
            for (int j = 0; j < CPB; ++j) {
                const int qj = q0 + j;
                if (qj > 1022) break;            // block-uniform
                const float* f0 = &lds[j][0];
                const float* f1 = &lds[j + 1][0];
                float2 o;
                o.x = a00 * f0[o00] + a10 * f1[o10];
                o.y = a01 * f0[o01] + a11 * f1[o11];
                *(float2*)(orow_base + (size_t)qj * 1024 + r) = o;
            }
        }

        if (!have_next) break;

        // All waves' extraction reads are consumed (stores issued) before
        // arrival here; barrier alone protects lds from next FFT's writes
        // (first DS write of next iter is deep inside fft_rest).
        asm volatile("" ::: "memory");
        __builtin_amdgcn_s_barrier();
        asm volatile("" ::: "memory");

        g = gn; b = bn; cb = cbn; act = actn;
    }
}

extern "C" void kernel_launch(void* const* d_in, const int* in_sizes, int n_in,
                              void* d_out, int out_size, void* d_ws, size_t ws_size,
                              hipStream_t stream) {
    const float* signal = (const float*)d_in[0];
    const float* window = (const float*)d_in[1];
    float* out = (float*)d_out;
    // 1024 persistent blocks (4/CU), grid-striding 4704 chunk-groups.
    imdct_kernel<<<dim3(GRID), dim3(512), 0, stream>>>(signal, window, out);
}

// Round 6
// 255.725 us; speedup vs baseline: 1.4139x; 1.3558x over previous
//
#include <hip/hip_runtime.h>

// FastIMDCT4: B=32, T=1024, n_fft=2048, hop=1024.
// out[b, q*1024+r] = frames[b,q,1024+r] + frames[b,q+1,r], q in [0,1023)
// frames[m] = sign[m]*window[m]/512 * inter[post[m]];  inter from 512-pt FFT.
//
// R3: 8-wave blocks, 7 chunks/block, reg 512-pt FFT -> LDS -> extract. 82.9us.
// R4: LDS twiddles: VALU 75->48%, dur unchanged.
// R5: 8x8x8 FFT, DS halved, conflicts 4.9M->1.2M, dur unchanged.
//     => all pipes ~40-45%: convoy/latency-bound.
// R6: persistent+prefetch: VGPR 68 -> only 2/4 blocks/CU resident, half the
//     grid serialized -> 94.9us.
// R7: __launch_bounds__(512,8) acted as 8 BLOCKS/CU -> VGPR cap 32 -> spill
//     (FETCH 394MB/WRITE 406MB), 212us. But: 84% occupancy, HBM 3.9 TB/s.
// R8: amdgpu_waves_per_eu(8) ALSO capped at 32 (cap=256/N on this toolchain,
//     not 512/N) -> same spill, 197us @ 4.0 TB/s.
// R9: direct allocator budget: amdgpu_num_vgpr(64) (no waves-semantics
//     interpretation). True live set ~50-55 -> no spill expected; 64 VGPR =
//     8 waves/SIMD (CDNA standard, inclusive) -> 4 blocks/CU resident.
//     Code otherwise byte-identical to R8 (single-variable experiment).

#define CHUNKS 1023
#define CPB 7              // chunks per group
#define BPB 147            // groups per batch: ceil(1023/7)
#define NGROUPS (32 * BPB) // 4704
#define GRID 1024          // persistent blocks: 256 CU x 4

__device__ __forceinline__ float2 cmul(float2 a, float2 b) {
    return make_float2(a.x * b.x - a.y * b.y, a.x * b.y + a.y * b.x);
}
__device__ __forceinline__ float2 cadd(float2 a, float2 b) {
    return make_float2(a.x + b.x, a.y + b.y);
}
__device__ __forceinline__ float2 csub(float2 a, float2 b) {
    return make_float2(a.x - b.x, a.y - b.y);
}
// (cos,sin) of 2*pi*rev — v_cos_f32/v_sin_f32 take revolutions; |rev| < 1 here.
__device__ __forceinline__ float2 twid(float rev) {
    return make_float2(__builtin_amdgcn_cosf(rev), __builtin_amdgcn_sinf(rev));
}

// post[] / sign[] closed forms (verified R1/R2: absmax 9.8e-4):
__device__ __forceinline__ void postmap(int m, int& p, float& sgn) {
    bool even = ((m & 1) == 0);
    if (m < 512)       p = even ? (m + 512)  : (512 - m);
    else if (m < 1536) p = even ? (m - 511)  : (1535 - m);
    else               p = even ? (m - 1536) : (2560 - m);
    float s1 = even ? 1.0f : -1.0f;
    sgn = (m < 1536) ? s1 : -s1;
}

__device__ __forceinline__ int brev3(int r) {
    return ((r & 1) << 2) | (r & 2) | ((r >> 2) & 1);
}

// 8-pt DFT, natural input order, output digit d lives in reg brev3(d).
__device__ __forceinline__ void radix8(float2 c[8]) {
    const float RH = 0.70710678118654752f;
    {   // stage 1 (half=4)
        float2 u0 = c[0], u1 = c[1], u2 = c[2], u3 = c[3];
        float2 l0 = c[4], l1 = c[5], l2 = c[6], l3 = c[7];
        float2 t1 = csub(u1, l1), t2 = csub(u2, l2), t3 = csub(u3, l3);
        c[0] = cadd(u0, l0); c[4] = csub(u0, l0);
        c[1] = cadd(u1, l1); c[5] = cmul(make_float2(RH, -RH), t1);
        c[2] = cadd(u2, l2); c[6] = make_float2(t2.y, -t2.x);           // * -i
        c[3] = cadd(u3, l3); c[7] = cmul(make_float2(-RH, -RH), t3);
    }
    #pragma unroll
    for (int b = 0; b < 8; b += 4) {  // stage 2 (half=2)
        float2 u0 = c[b], u1 = c[b + 1], d0 = c[b + 2], d1 = c[b + 3];
        float2 t = csub(u1, d1);
        c[b] = cadd(u0, d0);
        c[b + 2] = csub(u0, d0);
        c[b + 1] = cadd(u1, d1);
        c[b + 3] = make_float2(t.y, -t.x);                              // * -i
    }
    #pragma unroll
    for (int b = 0; b < 8; b += 2) {  // stage 3 (half=1)
        float2 u = c[b], d = c[b + 1];
        c[b] = cadd(u, d); c[b + 1] = csub(u, d);
    }
}

// Apply w^digit to each reg (digit(r) = brev3(r)): power chain in digit order.
__device__ __forceinline__ void midchain(float2 c[8], float2 w) {
    float2 wc = w;
    c[4] = cmul(wc, c[4]);                    // digit 1
    wc = cmul(wc, w); c[2] = cmul(wc, c[2]);  // digit 2
    wc = cmul(wc, w); c[6] = cmul(wc, c[6]);  // digit 3
    wc = cmul(wc, w); c[1] = cmul(wc, c[1]);  // digit 4
    wc = cmul(wc, w); c[5] = cmul(wc, c[5]);  // digit 5
    wc = cmul(wc, w); c[3] = cmul(wc, c[3]);  // digit 6
    wc = cmul(wc, w); c[7] = cmul(wc, c[7]);  // digit 7
}

// W32^r = W2048^{64r} = exp(-2*pi*i*r/32), exact compile-time constants.
#define K32_DECL \
    const float K32C[8] = {1.0f, 0.98078528040323044913f, 0.92387953251128675613f, \
                           0.83146961230254523708f, 0.70710678118654752440f,       \
                           0.55557023301960222474f, 0.38268343236508977173f,       \
                           0.19509032201612826785f};                               \
    const float K32S[8] = {0.0f, -0.19509032201612826785f, -0.38268343236508977173f,\
                           -0.55557023301960222474f, -0.70710678118654752440f,     \
                           -0.83146961230254523708f, -0.92387953251128675613f,     \
                           -0.98078528040323044913f};

__device__ __forceinline__ void load_frame(const float* __restrict__ row, int lane,
                                           float2 v[8]) {
    const float2* row2 = (const float2*)row;
    #pragma unroll
    for (int r = 0; r < 8; ++r) v[r] = row2[64 * r + lane];   // 512B/instr coalesced
}

// Pre-twiddle: consumes v (dead afterwards), produces c.
// c_n = W2048^{n+1/8} * (row[2n] + i*row[1023-2n]); imag lives in lane^63's
// v[7-r].y. W2048^{64r+lane+1/8} = T1b[lane] * K32[r].
__device__ __forceinline__ void fft_pre(const float2 v[8], int lane, float2 c[8],
                                        const float2* __restrict__ T1b) {
    K32_DECL
    float2 base = T1b[lane];
    #pragma unroll
    for (int r = 0; r < 8; ++r) {
        float im = __shfl_xor(v[7 - r].y, 63);
        float2 tw = (r == 0) ? base : cmul(base, make_float2(K32C[r], K32S[r]));
        c[r] = cmul(tw, make_float2(v[r].x, im));
    }
}

// Remainder of the 512-pt FFT (8x8x8, verified R5): three radix-8 stages with
// two barrier-free per-wave LDS redistributes (XOR-swizzled, conflict-free) in
// the wave's own slot; natural-k split-plane store.
__device__ __forceinline__ void fft_rest(float2 c[8], int lane,
                                         float* __restrict__ planes,
                                         const float2* __restrict__ TM,
                                         const float2* __restrict__ TM2,
                                         const float2* __restrict__ TP2) {
    K32_DECL
    float2* scratch = (float2*)planes;
    const int lh = lane >> 3;
    const int ll = lane & 7;

    // stage 1: radix-8 over n1 -> digit k1 (reg brev3(k1))
    radix8(c);
    midchain(c, TM[lane]);                       // * W512^{n2*k1}, n2 = lane

    // redistribute 1: (k1 regs, lane=(m1,m0)) -> (m1 regs, lane=(k1,m0))
    // idx(k1,m1,m0) = k1*64 + (m1^k1)*8 + m0  (conflict-free both sides)
    #pragma unroll
    for (int r = 0; r < 8; ++r) {
        const int q = brev3(r);
        scratch[q * 64 + (lh ^ q) * 8 + ll] = c[r];
    }
    asm volatile("" ::: "memory");
    #pragma unroll
    for (int r = 0; r < 8; ++r)
        c[r] = scratch[lh * 64 + (r ^ lh) * 8 + ll];   // now lh=k1, ll=m0

    // stage 2: radix-8 over m1 -> digit j1
    radix8(c);
    midchain(c, TM2[ll]);                        // * W64^{m0*j1}

    // redistribute 2: (j1 regs, lane=(k1,m0)) -> (m0 regs, lane=(k1,j1))
    // idx(k1,j1,m0) = k1*64 + (j1^k1)*8 + (m0^j1)
    #pragma unroll
    for (int r = 0; r < 8; ++r) {
        const int j1 = brev3(r);
        scratch[lh * 64 + (j1 ^ lh) * 8 + (ll ^ j1)] = c[r];
    }
    asm volatile("" ::: "memory");
    #pragma unroll
    for (int r = 0; r < 8; ++r)
        c[r] = scratch[lh * 64 + (ll ^ lh) * 8 + (r ^ ll)];  // now ll = j1

    // stage 3: radix-8 over m0 -> digit j2
    radix8(c);

    // post twiddle + natural-order store: k = 64*j2 + 8*j1 + k1
    float2 base2 = TP2[lane];
    const int kbase = 8 * ll + lh;
    #pragma unroll
    for (int j = 0; j < 8; ++j) {
        float2 tw = (j == 0) ? base2 : cmul(base2, make_float2(K32C[j], K32S[j]));
        float2 dv = cmul(tw, c[brev3(j)]);
        planes[64 * j + kbase]       = dv.x;
        planes[512 + 64 * j + kbase] = dv.y;
    }
}

// amdgpu_num_vgpr(64): DIRECT allocator budget (both waves-per-EU knobs were
// misinterpreted by this toolchain: N=8 -> cap 32, R7/R8). 64 VGPR = 8
// waves/SIMD (CDNA occupancy table, inclusive) -> 4 blocks/CU resident.
__global__ __launch_bounds__(512)
__attribute__((amdgpu_num_vgpr(64)))
void imdct_kernel(
        const float* __restrict__ signal,
        const float* __restrict__ window,
        float* __restrict__ out) {
    __shared__ float lds[8][1024];   // 8 frames x (Re[512] | Im[512]) = 32 KB
    __shared__ float2 T1b[64];       // W2048^{l+1/8}
    __shared__ float2 TM[64];        // W512^{l}
    __shared__ float2 TP2[64];       // W2048^{8*(l&7)+(l>>3)+1/8}
    __shared__ float2 TM2[8];        // W64^{l}

    const int tid = threadIdx.x;
    const int lane = tid & 63;
    const int w = tid >> 6;

    // ---- table init: once per persistent block ----
    if (tid < 64) {
        T1b[tid] = twid(-((float)tid + 0.125f) * (1.0f / 2048.0f));
        TM[tid]  = twid(-(float)tid * (1.0f / 512.0f));
        TP2[tid] = twid(-((float)(8 * (tid & 7) + (tid >> 3)) + 0.125f) * (1.0f / 2048.0f));
    }
    if (tid < 8) TM2[tid] = twid(-(float)tid * (1.0f / 64.0f));

    // ---- extraction constants (tid-only, persistent-loop invariant).
    // Offsets packed 2-per-reg so only 2 VGPRs stay live through the FFT;
    // unpacked after c[] dies. Coefficients: 4 VGPRs.
    float a00, a01, a10, a11;
    unsigned po_hi, po_lo;           // (o01<<16)|o00, (o11<<16)|o10
    {
        const int r = 2 * tid;
        int p00, p01, p10, p11; float s00, s01, s10, s11;
        postmap(1024 + r,     p00, s00);
        postmap(1024 + r + 1, p01, s01);
        postmap(r,            p10, s10);
        postmap(r + 1,        p11, s11);
        const float2 wh = *(const float2*)(window + 1024 + r);
        const float2 wl = *(const float2*)(window + r);
        a00 = s00 * wh.x * (1.0f / 512.0f);
        a01 = s01 * wh.y * (1.0f / 512.0f);
        a10 = s10 * wl.x * (1.0f / 512.0f);
        a11 = s11 * wl.y * (1.0f / 512.0f);
        const unsigned o00 = (p00 & 1) * 512 + (p00 >> 1);
        const unsigned o01 = (p01 & 1) * 512 + (p01 >> 1);
        const unsigned o10 = (p10 & 1) * 512 + (p10 >> 1);
        const unsigned o11 = (p11 & 1) * 512 + (p11 >> 1);
        po_hi = (o01 << 16) | o00;
        po_lo = (o11 << 16) | o10;
    }

    // ---- prologue: first group's loads ----
    int g = blockIdx.x;            // < 1024 < NGROUPS
    int b = g / BPB;
    int cb = g - b * BPB;          // group index within batch
    bool act = (cb * CPB + w <= 1023);
    float2 v[8];
    if (act) load_frame(signal + (size_t)(b * 1024 + cb * CPB + w) * 1024, lane, v);
    __syncthreads();   // tables visible (full drain OK once, in prologue)

    for (;;) {
        // Pre-twiddle consumes v -> c; v is then free for the prefetch.
        float2 c[8];
        if (act) fft_pre(v, lane, c, T1b);

        // Next-group bookkeeping, division-free: +1024 groups = +6 batches
        // + 142 within-batch (1024 = 6*147 + 142).
        const int gn = g + GRID;
        const bool have_next = (gn < NGROUPS);
        int bn = b, cbn = cb;
        if (have_next) {
            bn = b + 6; cbn = cb + (GRID - 6 * BPB);
            if (cbn >= BPB) { cbn -= BPB; bn += 1; }
        }
        const bool actn = have_next && (cbn * CPB + w <= 1023);
        // Prefetch NOW: latency hides under fft_rest (~800+ cyc) + extraction.
        if (actn) load_frame(signal + (size_t)(bn * 1024 + cbn * CPB + w) * 1024, lane, v);
        __builtin_amdgcn_sched_barrier(0);   // pin prefetch issue before FFT body

        if (act) fft_rest(c, lane, &lds[w][0], TM, TM2, TP2);

        // Raw barrier with lgkmcnt(0) only: planes visible to all waves, but
        // prefetch loads (vmcnt) stay in flight across the barrier.
        asm volatile("s_waitcnt lgkmcnt(0)" ::: "memory");
        __builtin_amdgcn_sched_barrier(0);
        __builtin_amdgcn_s_barrier();
        asm volatile("" ::: "memory");

        // Extraction for group g. c[] is dead here: unpack offsets into the
        // freed registers. Stores drain under the next iteration's FFT.
        {
            const int o00 = po_hi & 0xFFFF, o01 = po_hi >> 16;
            const int o10 = po_lo & 0xFFFF, o11 = po_lo >> 16;
            const int r = 2 * tid;
            const int q0 = cb * CPB;
            float* orow_base = out + (size_t)b * (CHUNKS * 1024);
            #pragma unroll
            for (int j = 0; j < CPB; ++j) {
                const int qj = q0 + j;
                if (qj > 1022) break;            // block-uniform
                const float* f0 = &lds[j][0];
                const float* f1 = &lds[j + 1][0];
                float2 o;
                o.x = a00 * f0[o00] + a10 * f1[o10];
                o.y = a01 * f0[o01] + a11 * f1[o11];
                *(float2*)(orow_base + (size_t)qj * 1024 + r) = o;
            }
        }

        if (!have_next) break;

        // All waves' extraction reads are consumed (stores issued) before
        // arrival here; barrier alone protects lds from next FFT's writes
        // (first DS write of next iter is deep inside fft_rest).
        asm volatile("" ::: "memory");
        __builtin_amdgcn_s_barrier();
        asm volatile("" ::: "memory");

        g = gn; b = bn; cb = cbn; act = actn;
    }
}

extern "C" void kernel_launch(void* const* d_in, const int* in_sizes, int n_in,
                              void* d_out, int out_size, void* d_ws, size_t ws_size,
                              hipStream_t stream) {
    const float* signal = (const float*)d_in[0];
    const float* window = (const float*)d_in[1];
    float* out = (float*)d_out;
    // 1024 persistent blocks (4/CU), grid-striding 4704 chunk-groups.
    imdct_kernel<<<dim3(GRID), dim3(512), 0, stream>>>(signal, window, out);
}

// Round 7
// 232.835 us; speedup vs baseline: 1.5529x; 1.0983x over previous
//
#include <hip/hip_runtime.h>

// FastIMDCT4: B=32, T=1024, n_fft=2048, hop=1024.
// out[b, q*1024+r] = frames[b,q,1024+r] + frames[b,q+1,r], q in [0,1023)
// frames[m] = sign[m]*window[m]/512 * inter[post[m]];  inter from 512-pt FFT.
//
// R3: 8-wave blocks, CPB=7, reg 512-pt FFT -> LDS -> extract. 82.9us.
// R4: LDS twiddles: VALU 75->48%, dur unchanged.
// R5: 8x8x8 FFT, DS halved, conflicts 4.9M->1.2M, dur unchanged.
//     => all pipes ~40-50%: convoy or dep-chain bound.
// R6-R9: persistent+prefetch arc DEAD: every occupancy knob failed
//     (VGPR 68 -> 2 blocks; launch_bounds(512,8) -> cap 32 + spill;
//     waves_per_eu(8) -> cap 32 + spill; num_vgpr(64) -> 64 is EXCLUSIVE,
//     still 2 blocks/CU + spill, 96us). Facts kept: mem system does 4 TB/s;
//     persistent residency is fine; 64-VGPR boundary halves waves.
// R10: discriminate convoy vs dep-chain WITHOUT fragile machinery:
//     4-wave blocks (256 thr), CPB=3 -> LDS 18KB -> 8 independent blocks/CU
//     (was 4), barrier scope halved, natural de-phasing across 10912 blocks.
//     1023 = 3*341 exactly -> zero tail divergence. Cost: FFT/chunk 8/7->4/3.
//     No attributes, no persistence: VGPR expected ~50 naturally.

#define CHUNKS 1023
#define CPB 3              // chunks per block
#define GPB 341            // groups per batch: 1023/3 exact
#define GRID (32 * GPB)    // 10912 blocks

__device__ __forceinline__ float2 cmul(float2 a, float2 b) {
    return make_float2(a.x * b.x - a.y * b.y, a.x * b.y + a.y * b.x);
}
__device__ __forceinline__ float2 cadd(float2 a, float2 b) {
    return make_float2(a.x + b.x, a.y + b.y);
}
__device__ __forceinline__ float2 csub(float2 a, float2 b) {
    return make_float2(a.x - b.x, a.y - b.y);
}
// (cos,sin) of 2*pi*rev — v_cos_f32/v_sin_f32 take revolutions; |rev| < 1 here.
__device__ __forceinline__ float2 twid(float rev) {
    return make_float2(__builtin_amdgcn_cosf(rev), __builtin_amdgcn_sinf(rev));
}

// post[] / sign[] closed forms (verified R1/R2: absmax 9.8e-4):
__device__ __forceinline__ void postmap(int m, int& p, float& sgn) {
    bool even = ((m & 1) == 0);
    if (m < 512)       p = even ? (m + 512)  : (512 - m);
    else if (m < 1536) p = even ? (m - 511)  : (1535 - m);
    else               p = even ? (m - 1536) : (2560 - m);
    float s1 = even ? 1.0f : -1.0f;
    sgn = (m < 1536) ? s1 : -s1;
}

__device__ __forceinline__ int brev3(int r) {
    return ((r & 1) << 2) | (r & 2) | ((r >> 2) & 1);
}

// 8-pt DFT, natural input order, output digit d lives in reg brev3(d).
__device__ __forceinline__ void radix8(float2 c[8]) {
    const float RH = 0.70710678118654752f;
    {   // stage 1 (half=4)
        float2 u0 = c[0], u1 = c[1], u2 = c[2], u3 = c[3];
        float2 l0 = c[4], l1 = c[5], l2 = c[6], l3 = c[7];
        float2 t1 = csub(u1, l1), t2 = csub(u2, l2), t3 = csub(u3, l3);
        c[0] = cadd(u0, l0); c[4] = csub(u0, l0);
        c[1] = cadd(u1, l1); c[5] = cmul(make_float2(RH, -RH), t1);
        c[2] = cadd(u2, l2); c[6] = make_float2(t2.y, -t2.x);           // * -i
        c[3] = cadd(u3, l3); c[7] = cmul(make_float2(-RH, -RH), t3);
    }
    #pragma unroll
    for (int b = 0; b < 8; b += 4) {  // stage 2 (half=2)
        float2 u0 = c[b], u1 = c[b + 1], d0 = c[b + 2], d1 = c[b + 3];
        float2 t = csub(u1, d1);
        c[b] = cadd(u0, d0);
        c[b + 2] = csub(u0, d0);
        c[b + 1] = cadd(u1, d1);
        c[b + 3] = make_float2(t.y, -t.x);                              // * -i
    }
    #pragma unroll
    for (int b = 0; b < 8; b += 2) {  // stage 3 (half=1)
        float2 u = c[b], d = c[b + 1];
        c[b] = cadd(u, d); c[b + 1] = csub(u, d);
    }
}

// Apply w^digit to each reg (digit(r) = brev3(r)): power chain in digit order.
__device__ __forceinline__ void midchain(float2 c[8], float2 w) {
    float2 wc = w;
    c[4] = cmul(wc, c[4]);                    // digit 1
    wc = cmul(wc, w); c[2] = cmul(wc, c[2]);  // digit 2
    wc = cmul(wc, w); c[6] = cmul(wc, c[6]);  // digit 3
    wc = cmul(wc, w); c[1] = cmul(wc, c[1]);  // digit 4
    wc = cmul(wc, w); c[5] = cmul(wc, c[5]);  // digit 5
    wc = cmul(wc, w); c[3] = cmul(wc, c[3]);  // digit 6
    wc = cmul(wc, w); c[7] = cmul(wc, c[7]);  // digit 7
}

// W32^r = W2048^{64r} = exp(-2*pi*i*r/32), exact compile-time constants.
#define K32_DECL \
    const float K32C[8] = {1.0f, 0.98078528040323044913f, 0.92387953251128675613f, \
                           0.83146961230254523708f, 0.70710678118654752440f,       \
                           0.55557023301960222474f, 0.38268343236508977173f,       \
                           0.19509032201612826785f};                               \
    const float K32S[8] = {0.0f, -0.19509032201612826785f, -0.38268343236508977173f,\
                           -0.55557023301960222474f, -0.70710678118654752440f,     \
                           -0.83146961230254523708f, -0.92387953251128675613f,     \
                           -0.98078528040323044913f};

__device__ __forceinline__ void load_frame(const float* __restrict__ row, int lane,
                                           float2 v[8]) {
    const float2* row2 = (const float2*)row;
    #pragma unroll
    for (int r = 0; r < 8; ++r) v[r] = row2[64 * r + lane];   // 512B/instr coalesced
}

// Pre-twiddle: consumes v (dead afterwards), produces c.
// c_n = W2048^{n+1/8} * (row[2n] + i*row[1023-2n]); imag lives in lane^63's
// v[7-r].y. W2048^{64r+lane+1/8} = T1b[lane] * K32[r].
__device__ __forceinline__ void fft_pre(const float2 v[8], int lane, float2 c[8],
                                        const float2* __restrict__ T1b) {
    K32_DECL
    float2 base = T1b[lane];
    #pragma unroll
    for (int r = 0; r < 8; ++r) {
        float im = __shfl_xor(v[7 - r].y, 63);
        float2 tw = (r == 0) ? base : cmul(base, make_float2(K32C[r], K32S[r]));
        c[r] = cmul(tw, make_float2(v[r].x, im));
    }
}

// Remainder of the 512-pt FFT (8x8x8, verified R5): three radix-8 stages with
// two barrier-free per-wave LDS redistributes (XOR-swizzled, conflict-free) in
// the wave's own slot; natural-k split-plane store.
__device__ __forceinline__ void fft_rest(float2 c[8], int lane,
                                         float* __restrict__ planes,
                                         const float2* __restrict__ TM,
                                         const float2* __restrict__ TM2,
                                         const float2* __restrict__ TP2) {
    K32_DECL
    float2* scratch = (float2*)planes;
    const int lh = lane >> 3;
    const int ll = lane & 7;

    // stage 1: radix-8 over n1 -> digit k1 (reg brev3(k1))
    radix8(c);
    midchain(c, TM[lane]);                       // * W512^{n2*k1}, n2 = lane

    // redistribute 1: (k1 regs, lane=(m1,m0)) -> (m1 regs, lane=(k1,m0))
    // idx(k1,m1,m0) = k1*64 + (m1^k1)*8 + m0  (conflict-free both sides)
    #pragma unroll
    for (int r = 0; r < 8; ++r) {
        const int q = brev3(r);
        scratch[q * 64 + (lh ^ q) * 8 + ll] = c[r];
    }
    asm volatile("" ::: "memory");
    #pragma unroll
    for (int r = 0; r < 8; ++r)
        c[r] = scratch[lh * 64 + (r ^ lh) * 8 + ll];   // now lh=k1, ll=m0

    // stage 2: radix-8 over m1 -> digit j1
    radix8(c);
    midchain(c, TM2[ll]);                        // * W64^{m0*j1}

    // redistribute 2: (j1 regs, lane=(k1,m0)) -> (m0 regs, lane=(k1,j1))
    // idx(k1,j1,m0) = k1*64 + (j1^k1)*8 + (m0^j1)
    #pragma unroll
    for (int r = 0; r < 8; ++r) {
        const int j1 = brev3(r);
        scratch[lh * 64 + (j1 ^ lh) * 8 + (ll ^ j1)] = c[r];
    }
    asm volatile("" ::: "memory");
    #pragma unroll
    for (int r = 0; r < 8; ++r)
        c[r] = scratch[lh * 64 + (ll ^ lh) * 8 + (r ^ ll)];  // now ll = j1

    // stage 3: radix-8 over m0 -> digit j2
    radix8(c);

    // post twiddle + natural-order store: k = 64*j2 + 8*j1 + k1
    float2 base2 = TP2[lane];
    const int kbase = 8 * ll + lh;
    #pragma unroll
    for (int j = 0; j < 8; ++j) {
        float2 tw = (j == 0) ? base2 : cmul(base2, make_float2(K32C[j], K32S[j]));
        float2 dv = cmul(tw, c[brev3(j)]);
        planes[64 * j + kbase]       = dv.x;
        planes[512 + 64 * j + kbase] = dv.y;
    }
}

// 4 waves, no occupancy attributes: natural VGPR (~50) keeps 8 waves/SIMD;
// LDS 18KB -> 8 blocks/CU (de-phased), 32 waves/CU.
__global__ __launch_bounds__(256) void imdct_kernel(
        const float* __restrict__ signal,
        const float* __restrict__ window,
        float* __restrict__ out) {
    __shared__ float lds[4][1024];   // 4 frames x (Re[512] | Im[512]) = 16 KB
    __shared__ float2 T1b[64];       // W2048^{l+1/8}
    __shared__ float2 TM[64];        // W512^{l}
    __shared__ float2 TP2[64];       // W2048^{8*(l&7)+(l>>3)+1/8}
    __shared__ float2 TM2[8];        // W64^{l}

    const int tid = threadIdx.x;
    const int lane = tid & 63;
    const int w = tid >> 6;

    // ---- group mapping: 1023 = 3*341 exactly, no tail anywhere ----
    const int bid = blockIdx.x;
    const int b = bid / GPB;
    const int gb = bid - b * GPB;
    const int q0 = gb * CPB;         // chunks q0..q0+2; frames q0..q0+3

    // Issue the frame loads first so HBM latency overlaps table init below.
    float2 v[8];
    load_frame(signal + (size_t)(b * 1024 + q0 + w) * 1024, lane, v);

    // ---- table init ----
    if (tid < 64) {
        T1b[tid] = twid(-((float)tid + 0.125f) * (1.0f / 2048.0f));
        TM[tid]  = twid(-(float)tid * (1.0f / 512.0f));
        TP2[tid] = twid(-((float)(8 * (tid & 7) + (tid >> 3)) + 0.125f) * (1.0f / 2048.0f));
    }
    if (tid < 8) TM2[tid] = twid(-(float)tid * (1.0f / 64.0f));

    // ---- extraction constants: thread t handles output pairs rA=2t and
    // rB=2t+512 of each chunk. 8 coeffs + 8 offsets (packed 16-bit).
    float aA00, aA01, aA10, aA11, aB00, aB01, aB10, aB11;
    unsigned poA0, poA1, poB0, poB1;
    {
        const int rA = 2 * tid;          // [0,512)
        const int rB = rA + 512;         // [512,1024)
        int p; float s;
        unsigned o;
        // pair A, frame qj (upper half m=1024+rA in [1024,1536))
        postmap(1024 + rA, p, s);     o  = (p & 1) * 512 + (p >> 1);
        aA00 = s;                     poA0 = o;
        postmap(1024 + rA + 1, p, s); o  = (p & 1) * 512 + (p >> 1);
        aA01 = s;                     poA0 |= o << 16;
        // pair A, frame qj+1 (lower half m=rA in [0,512))
        postmap(rA, p, s);            o  = (p & 1) * 512 + (p >> 1);
        aA10 = s;                     poA1 = o;
        postmap(rA + 1, p, s);        o  = (p & 1) * 512 + (p >> 1);
        aA11 = s;                     poA1 |= o << 16;
        // pair B, frame qj (m=1024+rB in [1536,2048))
        postmap(1024 + rB, p, s);     o  = (p & 1) * 512 + (p >> 1);
        aB00 = s;                     poB0 = o;
        postmap(1024 + rB + 1, p, s); o  = (p & 1) * 512 + (p >> 1);
        aB01 = s;                     poB0 |= o << 16;
        // pair B, frame qj+1 (m=rB in [512,1024))
        postmap(rB, p, s);            o  = (p & 1) * 512 + (p >> 1);
        aB10 = s;                     poB1 = o;
        postmap(rB + 1, p, s);        o  = (p & 1) * 512 + (p >> 1);
        aB11 = s;                     poB1 |= o << 16;

        const float2 whA = *(const float2*)(window + 1024 + rA);
        const float2 wlA = *(const float2*)(window + rA);
        const float2 whB = *(const float2*)(window + 1024 + rB);
        const float2 wlB = *(const float2*)(window + rB);
        aA00 *= whA.x * (1.0f / 512.0f);  aA01 *= whA.y * (1.0f / 512.0f);
        aA10 *= wlA.x * (1.0f / 512.0f);  aA11 *= wlA.y * (1.0f / 512.0f);
        aB00 *= whB.x * (1.0f / 512.0f);  aB01 *= whB.y * (1.0f / 512.0f);
        aB10 *= wlB.x * (1.0f / 512.0f);  aB11 *= wlB.y * (1.0f / 512.0f);
    }
    __syncthreads();   // tables visible

    // ---- Phase 1: each wave FFTs frame q0+w into its LDS slot ----
    {
        float2 c[8];
        fft_pre(v, lane, c, T1b);
        fft_rest(c, lane, &lds[w][0], TM, TM2, TP2);
    }
    __syncthreads();

    // ---- Phase 2: extraction for 3 chunks ----
    const int oA00 = poA0 & 0xFFFF, oA01 = poA0 >> 16;
    const int oA10 = poA1 & 0xFFFF, oA11 = poA1 >> 16;
    const int oB00 = poB0 & 0xFFFF, oB01 = poB0 >> 16;
    const int oB10 = poB1 & 0xFFFF, oB11 = poB1 >> 16;
    const int rA = 2 * tid;
    float* orow_base = out + (size_t)b * (CHUNKS * 1024) + (size_t)q0 * 1024;

    #pragma unroll
    for (int j = 0; j < CPB; ++j) {
        const float* f0 = &lds[j][0];
        const float* f1 = &lds[j + 1][0];
        float2 o0, o1;
        o0.x = aA00 * f0[oA00] + aA10 * f1[oA10];
        o0.y = aA01 * f0[oA01] + aA11 * f1[oA11];
        o1.x = aB00 * f0[oB00] + aB10 * f1[oB10];
        o1.y = aB01 * f0[oB01] + aB11 * f1[oB11];
        float* orow = orow_base + (size_t)j * 1024;
        *(float2*)(orow + rA)       = o0;
        *(float2*)(orow + rA + 512) = o1;
    }
}

extern "C" void kernel_launch(void* const* d_in, const int* in_sizes, int n_in,
                              void* d_out, int out_size, void* d_ws, size_t ws_size,
                              hipStream_t stream) {
    const float* signal = (const float*)d_in[0];
    const float* window = (const float*)d_in[1];
    float* out = (float*)d_out;
    // 32 batches x 341 groups (3 chunks each), 256 threads (4 waves) per block
    imdct_kernel<<<dim3(GRID), dim3(256), 0, stream>>>(signal, window, out);
}